// Round 15
// baseline (76.409 us; speedup 1.0000x reference)
//
#include <hip/hip_runtime.h>

// ---------------------------------------------------------------------------
// DeepFM forward, MI355X. Round 15: R14 base (73.8us) + GEMM pipeline depth.
//  (1) gemm1: depth-3 prefetch, 4 LDS buffers, vmcnt(8) (was depth-2/vmcnt4)
//  (2) finstats1 prescales W2s[n][k] = W2T[n][k]*a1[k] (each block scales the
//      cols whose a1 it computed -> no extra kernel, no sync needed)
//  (3) gemm2 rewritten on gemm1's template: full-async A+B (global_load_lds),
//      BK=32, depth-3/4-buffer counted vmcnt(6), T2 swizzle. No per-iter
//      vmcnt(0) drain (old reg-staged-B __syncthreads forced one).
// Embed: R14 (LDS-staged inputs; gathers at DRAM random-64B floor).
// Algebra: b1/bt1/b2 cancel; BN1 = diag(a1) folded via W2s prescale.
// ---------------------------------------------------------------------------

#define B_ROWS 16384
#define VOCAB 100000
#define D0 640
#define H1 512
#define H2 256
#define EPSV 1e-5f

typedef short bf16x8 __attribute__((ext_vector_type(8)));
typedef float f32x4 __attribute__((ext_vector_type(4)));
typedef unsigned short u16;

struct Params {
    const int* Xi; const float* Xv; const float* bias;
    const float* dw1; const float* db1; const float* e1;
    const float* dw2; const float* db2; const float* e2;
    const float* W1; const float* g1; const float* bt1;
    const float* W2; const float* g2; const float* bt2;
    u16* so_bf; float* partial; u16* W1T; u16* W2T; u16* W2s;
    float* psum1; float* psq1; float* psum2; float* psq2;
    float* a1; float* a2; float* c2;
    u16* Z1bf; u16* Z2bf; float* out;
};

__device__ inline u16 f2bf(float x) {
    unsigned u = __float_as_uint(x);
    return (u16)((u + 0x7fffu + ((u >> 16) & 1u)) >> 16);   // RNE
}
__device__ inline float bf2f(unsigned b) {
    return __uint_as_float((b & 0xffffu) << 16);
}
__device__ inline void async16(const void* g, void* l) {
    __builtin_amdgcn_global_load_lds(
        (const __attribute__((address_space(1))) void*)g,
        (__attribute__((address_space(3))) void*)l, 16, 0, 0);
}

// ---------------------------------------------------------------------------
// K1: fused weight transposes (blocks 0..447) + embed/FM. (== R14)
__global__ __launch_bounds__(256) void embed_prep_k(Params p) {
    __shared__ float tile[32][33];
    __shared__ u16 so_lds[16][648];                  // +8 pad
    __shared__ __align__(16) int   xi_lds[16][40];
    __shared__ __align__(16) float xv_lds[16][40];
    __shared__ __align__(16) float w_lds[4][208];    // dw1,db1,dw2,db2
    const int bid = blockIdx.x, tid = threadIdx.x;
    const int rblk = (bid & 7) * 128 + (bid >> 3);   // XCD-aligned row-group

    if (tid < 160) {
        ((uint4*)&xi_lds[0][0])[tid] = ((const uint4*)(p.Xi + (size_t)rblk * 16 * 40))[tid];
        ((uint4*)&xv_lds[0][0])[tid] = ((const uint4*)(p.Xv + (size_t)rblk * 16 * 40))[tid];
    }
    if (tid < 52)        ((uint4*)&w_lds[0][0])[tid]       = ((const uint4*)p.dw1)[tid];
    else if (tid < 104)  ((uint4*)&w_lds[1][0])[tid - 52]  = ((const uint4*)p.db1)[tid - 52];
    else if (tid < 156)  ((uint4*)&w_lds[2][0])[tid - 104] = ((const uint4*)p.dw2)[tid - 104];
    else if (tid < 208)  ((uint4*)&w_lds[3][0])[tid - 156] = ((const uint4*)p.db2)[tid - 156];

    if (bid < 448) {            // transpose W1 (320 tiles) / W2 (128 tiles)
        const float* W; u16* WT; int K, N, k0, n0;
        if (bid < 320) { W = p.W1; WT = p.W1T; K = D0; N = H1; k0 = (bid % 20) * 32; n0 = (bid / 20) * 32; }
        else { int b2 = bid - 320; W = p.W2; WT = p.W2T; K = H1; N = H2; k0 = (b2 % 16) * 32; n0 = (b2 / 16) * 32; }
        int tx = tid & 31, ty4 = (tid >> 5) * 4;
#pragma unroll
        for (int r = 0; r < 4; ++r)
            tile[ty4 + r][tx] = W[(size_t)(k0 + ty4 + r) * N + n0 + tx];
        __syncthreads();
#pragma unroll
        for (int r = 0; r < 4; ++r)
            WT[(size_t)(n0 + ty4 + r) * K + k0 + tx] = f2bf(tile[tx][ty4 + r]);
    }
    __syncthreads();

    const int e = tid & 15;
    const int r = tid >> 4;
    const int b = rblk * 16 + r;

    float accf = 0.f, s1 = 0.f, sq = 0.f;
#pragma unroll
    for (int f = 0; f < 13; ++f) {
        float x = (float)xi_lds[r][f];
        float xv = xv_lds[r][f];
        float fo = (x * w_lds[0][f * 16 + e] + w_lds[1][f * 16 + e]) * xv;
        float so = (x * w_lds[2][f * 16 + e] + w_lds[3][f * 16 + e]) * xv;
        accf += fo; s1 += so; sq += so * so;
        so_lds[r][f * 16 + e] = f2bf(so);
    }
#pragma unroll 1
    for (int c = 0; c < 3; ++c) {
        const int base = 13 + c * 9;
        int   ix[9]; float xv9[9], v1[9], v2[9];
#pragma unroll
        for (int s = 0; s < 9; ++s) { ix[s] = xi_lds[r][base + s]; xv9[s] = xv_lds[r][base + s]; }
#pragma unroll
        for (int s = 0; s < 9; ++s) {
            size_t off = (size_t)(base - 13 + s) * (VOCAB * 16) + (size_t)ix[s] * 16 + e;
            v1[s] = p.e1[off];
            v2[s] = p.e2[off];
        }
#pragma unroll
        for (int s = 0; s < 9; ++s) {
            float fo = v1[s] * xv9[s], so = v2[s] * xv9[s];
            accf += fo; s1 += so; sq += so * so;
            so_lds[r][(base + s) * 16 + e] = f2bf(so);
        }
    }
    float val = accf + 0.5f * (s1 * s1 - sq);
    val += __shfl_xor(val, 1); val += __shfl_xor(val, 2);
    val += __shfl_xor(val, 4); val += __shfl_xor(val, 8);
    if (e == 0) p.partial[b] = val + p.bias[b];

    __syncthreads();
    uint4* gdst = (uint4*)(p.so_bf + (size_t)rblk * 16 * D0);
#pragma unroll
    for (int k = 0; k < 5; ++k) {
        int v = k * 256 + tid;
        int row = v / 80, c16 = v - row * 80;
        gdst[v] = *(const uint4*)&so_lds[row][c16 * 8];
    }
}

// ---------------------------------------------------------------------------
// K2: Z1 = so @ W1T^T (NT). 128x128 tile, BK=32, depth-3 prefetch, 4 LDS
// buffers, counted vmcnt(8) + T2 swizzle. Fused column stats.
__global__ __launch_bounds__(256) void gemm1_k(Params p) {
    __shared__ u16 As[4][128 * 32];
    __shared__ u16 Bs[4][128 * 32];
    const int tid = threadIdx.x, lane = tid & 63, w = tid >> 6;
    const int bid = (int)blockIdx.x;
    const int g = bid >> 3, x = bid & 7;
    const int mt = x * 16 + (g >> 2), nt = g & 3;
    const int m0 = mt * 128, n0 = nt * 128;
    const int wr = w >> 1, wc = w & 1;

    f32x4 acc[4][4] = {};

    auto stage = [&](int buf, int kt) {         // 4 asyncs/thread
#pragma unroll
        for (int j = 0; j < 2; ++j) {
            int s = j * 256 + tid;
            int row = s >> 2;
            int c8 = ((s ^ (s >> 3)) & 3) * 8;  // (slot) ^ ((row>>1)&3)
            async16(p.so_bf + (size_t)(m0 + row) * D0 + kt + c8,
                    &As[buf][(j * 256 + w * 64) * 8]);
            async16(p.W1T + (size_t)(n0 + row) * D0 + kt + c8,
                    &Bs[buf][(j * 256 + w * 64) * 8]);
        }
    };

    const int NT = D0 / 32;                     // 20
    stage(0, 0);
    stage(1, 32);
    stage(2, 64);
    for (int t = 0; t < NT; ++t) {
        if (t < NT - 2)       asm volatile("s_waitcnt vmcnt(8)" ::: "memory");
        else if (t == NT - 2) asm volatile("s_waitcnt vmcnt(4)" ::: "memory");
        else                  asm volatile("s_waitcnt vmcnt(0)" ::: "memory");
        __builtin_amdgcn_s_barrier();
        __builtin_amdgcn_sched_barrier(0);
        if (t + 3 < NT) stage((t + 3) & 3, (t + 3) * 32);
        const u16* Ac = As[t & 3];
        const u16* Bc = Bs[t & 3];
        const int gq = lane >> 4;
        bf16x8 af[4], bfr[4];
#pragma unroll
        for (int i = 0; i < 4; ++i) {
            int ar = wr * 64 + i * 16 + (lane & 15);
            af[i] = *(const bf16x8*)&Ac[ar * 32 + ((gq ^ ((ar >> 1) & 3)) * 8)];
            int br = wc * 64 + i * 16 + (lane & 15);
            bfr[i] = *(const bf16x8*)&Bc[br * 32 + ((gq ^ ((br >> 1) & 3)) * 8)];
        }
#pragma unroll
        for (int i = 0; i < 4; ++i)
#pragma unroll
            for (int j2 = 0; j2 < 4; ++j2)
                acc[i][j2] = __builtin_amdgcn_mfma_f32_16x16x32_bf16(
                    af[i], bfr[j2], acc[i][j2], 0, 0, 0);
    }
#pragma unroll
    for (int i = 0; i < 4; ++i)
#pragma unroll
        for (int j2 = 0; j2 < 4; ++j2) {
            int row = m0 + wr * 64 + i * 16 + (lane >> 4) * 4;
            int col = n0 + wc * 64 + j2 * 16 + (lane & 15);
#pragma unroll
            for (int q = 0; q < 4; ++q)
                p.Z1bf[(size_t)(row + q) * H1 + col] = f2bf(acc[i][j2][q]);
        }
    const int chunk = mt * 2 + wr;               // 256 chunks
#pragma unroll
    for (int j2 = 0; j2 < 4; ++j2) {
        float s = 0.f, q = 0.f;
#pragma unroll
        for (int i = 0; i < 4; ++i)
#pragma unroll
            for (int qq = 0; qq < 4; ++qq) { float v = acc[i][j2][qq]; s += v; q += v * v; }
        s += __shfl_xor(s, 16); s += __shfl_xor(s, 32);
        q += __shfl_xor(q, 16); q += __shfl_xor(q, 32);
        if (lane < 16) {
            int col = n0 + wc * 64 + j2 * 16 + lane;
            p.psum1[(size_t)chunk * H1 + col] = s;
            p.psq1[(size_t)chunk * H1 + col] = q;
        }
    }
}

// ---------------------------------------------------------------------------
// K3: a1 + W2s prescale. 64 blocks, 32 lanes/col; after the tree reduce every
// lane has the totals, so the group scales its own column of W2T.
__global__ __launch_bounds__(256) void finstats1_k(Params p) {
    int col = blockIdx.x * 8 + (threadIdx.x >> 5);
    int l32 = threadIdx.x & 31;
    float s = 0.f, q = 0.f;
#pragma unroll
    for (int k = 0; k < 8; ++k) {
        int ch = k * 32 + l32;
        s += p.psum1[(size_t)ch * H1 + col];
        q += p.psq1[(size_t)ch * H1 + col];
    }
#pragma unroll
    for (int m = 1; m <= 16; m <<= 1) {
        s += __shfl_xor(s, m);
        q += __shfl_xor(q, m);
    }
    const float inv = 1.0f / (float)B_ROWS;
    float mean = s * inv;
    float var = q * inv - mean * mean;
    float av = p.g1[col] * rsqrtf(var + EPSV);
    if (l32 == 0) p.a1[col] = av;
    // W2s[n][col] = W2T[n][col] * a1[col]  (8 rows per lane)
#pragma unroll
    for (int k = 0; k < 8; ++k) {
        int n = k * 32 + l32;
        p.W2s[(size_t)n * H1 + col] = f2bf(bf2f(p.W2T[(size_t)n * H1 + col]) * av);
    }
}

// ---------------------------------------------------------------------------
// K4: Z2 = Z1 @ W2s^T (NT). 128x64 tile, BK=32, depth-3 prefetch, 4 buffers,
// counted vmcnt(6) + T2 swizzle — gemm1's template, full-async A and B.
__global__ __launch_bounds__(256) void gemm2_k(Params p) {
    __shared__ u16 As[4][128 * 32];
    __shared__ u16 Bs[4][64 * 32];
    const int tid = threadIdx.x, lane = tid & 63, w = tid >> 6;
    const int bid = (int)blockIdx.x;
    const int g = bid >> 3, x = bid & 7;
    const int mt = x * 16 + (g >> 2), nt = g & 3;
    const int m0 = mt * 128, n0 = nt * 64;
    const int wr = w >> 1, wc = w & 1;

    f32x4 acc[4][2] = {};

    auto stage = [&](int buf, int kt) {         // 3 asyncs/thread
#pragma unroll
        for (int j = 0; j < 2; ++j) {
            int s = j * 256 + tid;
            int row = s >> 2;
            int c8 = ((s ^ (s >> 3)) & 3) * 8;
            async16(p.Z1bf + (size_t)(m0 + row) * H1 + kt + c8,
                    &As[buf][(j * 256 + w * 64) * 8]);
        }
        {
            int s = tid;
            int row = s >> 2;
            int c8 = ((s ^ (s >> 3)) & 3) * 8;
            async16(p.W2s + (size_t)(n0 + row) * H1 + kt + c8,
                    &Bs[buf][(w * 64) * 8]);
        }
    };

    const int NT = H1 / 32;                     // 16
    stage(0, 0);
    stage(1, 32);
    stage(2, 64);
    for (int t = 0; t < NT; ++t) {
        if (t < NT - 2)       asm volatile("s_waitcnt vmcnt(6)" ::: "memory");
        else if (t == NT - 2) asm volatile("s_waitcnt vmcnt(3)" ::: "memory");
        else                  asm volatile("s_waitcnt vmcnt(0)" ::: "memory");
        __builtin_amdgcn_s_barrier();
        __builtin_amdgcn_sched_barrier(0);
        if (t + 3 < NT) stage((t + 3) & 3, (t + 3) * 32);
        const u16* Ac = As[t & 3];
        const u16* Bc = Bs[t & 3];
        const int gq = lane >> 4;
        bf16x8 af[4], bfr[2];
#pragma unroll
        for (int i = 0; i < 4; ++i) {
            int ar = wr * 64 + i * 16 + (lane & 15);
            af[i] = *(const bf16x8*)&Ac[ar * 32 + ((gq ^ ((ar >> 1) & 3)) * 8)];
        }
#pragma unroll
        for (int j2 = 0; j2 < 2; ++j2) {
            int br = wc * 32 + j2 * 16 + (lane & 15);
            bfr[j2] = *(const bf16x8*)&Bc[br * 32 + ((gq ^ ((br >> 1) & 3)) * 8)];
        }
#pragma unroll
        for (int i = 0; i < 4; ++i)
#pragma unroll
            for (int j2 = 0; j2 < 2; ++j2)
                acc[i][j2] = __builtin_amdgcn_mfma_f32_16x16x32_bf16(
                    af[i], bfr[j2], acc[i][j2], 0, 0, 0);
    }
#pragma unroll
    for (int i = 0; i < 4; ++i)
#pragma unroll
        for (int j2 = 0; j2 < 2; ++j2) {
            int row = m0 + wr * 64 + i * 16 + (lane >> 4) * 4;
            int col = n0 + wc * 32 + j2 * 16 + (lane & 15);
#pragma unroll
            for (int q = 0; q < 4; ++q)
                p.Z2bf[(size_t)(row + q) * H2 + col] = f2bf(acc[i][j2][q]);
        }
    const int chunk = mt * 2 + wr;               // 256 chunks
#pragma unroll
    for (int j2 = 0; j2 < 2; ++j2) {
        float s = 0.f, q = 0.f;
#pragma unroll
        for (int i = 0; i < 4; ++i)
#pragma unroll
            for (int qq = 0; qq < 4; ++qq) { float v = acc[i][j2][qq]; s += v; q += v * v; }
        s += __shfl_xor(s, 16); s += __shfl_xor(s, 32);
        q += __shfl_xor(q, 16); q += __shfl_xor(q, 32);
        if (lane < 16) {
            int col = n0 + wc * 32 + j2 * 16 + lane;
            p.psum2[(size_t)chunk * H2 + col] = s;
            p.psq2[(size_t)chunk * H2 + col] = q;
        }
    }
}

// ---------------------------------------------------------------------------
// K5: a2,c2. 32 blocks, 32 lanes/col, tree reduce. (== R14)
__global__ __launch_bounds__(256) void finstats2_k(Params p) {
    int col = blockIdx.x * 8 + (threadIdx.x >> 5);
    int l32 = threadIdx.x & 31;
    float s = 0.f, q = 0.f;
#pragma unroll
    for (int k = 0; k < 8; ++k) {
        int ch = k * 32 + l32;
        s += p.psum2[(size_t)ch * H2 + col];
        q += p.psq2[(size_t)ch * H2 + col];
    }
#pragma unroll
    for (int m = 1; m <= 16; m <<= 1) {
        s += __shfl_xor(s, m);
        q += __shfl_xor(q, m);
    }
    if (l32 == 0) {
        const float inv = 1.0f / (float)B_ROWS;
        float mean = s * inv;
        float var = q * inv - mean * mean;
        float av = p.g2[col] * rsqrtf(var + EPSV);
        p.a2[col] = av;
        p.c2[col] = p.bt2[col] - mean * av;
    }
}

// ---------------------------------------------------------------------------
// K6: out[b] = partial[b] + sum_c (Z2[b,c]*a2[c] + c2[c]). XCD-chained. (==R14)
__global__ __launch_bounds__(256) void final_k(Params p) {
    int w = threadIdx.x >> 6, lane = threadIdx.x & 63;
    int j = (int)blockIdx.x;
    int gblk = (j & 7) * 512 + (j >> 3);
    int b = gblk * 4 + w;
    ushort4 z4 = *(const ushort4*)(p.Z2bf + (size_t)b * H2 + lane * 4);
    float4 a = *(const float4*)(p.a2 + lane * 4);
    float4 c = *(const float4*)(p.c2 + lane * 4);
    float v = bf2f(z4.x) * a.x + c.x + bf2f(z4.y) * a.y + c.y
            + bf2f(z4.z) * a.z + c.z + bf2f(z4.w) * a.w + c.w;
#pragma unroll
    for (int m = 1; m < 64; m <<= 1) v += __shfl_xor(v, m);
    if (lane == 0) p.out[b] = p.partial[b] + v;
}

// ---------------------------------------------------------------------------
extern "C" void kernel_launch(void* const* d_in, const int* in_sizes, int n_in,
                              void* d_out, int out_size, void* d_ws, size_t ws_size,
                              hipStream_t stream)
{
    Params p;
    p.Xi   = (const int*)d_in[0];
    p.Xv   = (const float*)d_in[1];
    p.bias = (const float*)d_in[2];
    p.dw1  = (const float*)d_in[3];
    p.db1  = (const float*)d_in[4];
    p.e1   = (const float*)d_in[5];
    p.dw2  = (const float*)d_in[6];
    p.db2  = (const float*)d_in[7];
    p.e2   = (const float*)d_in[8];
    p.W1   = (const float*)d_in[9];
    // d_in[10] = b1: cancels in BN1 -> unused
    p.g1   = (const float*)d_in[11];
    p.bt1  = (const float*)d_in[12];   // col-const shift -> cancels in BN2 -> unused
    p.W2   = (const float*)d_in[13];
    // d_in[14] = b2: cancels in BN2 -> unused
    p.g2   = (const float*)d_in[15];
    p.bt2  = (const float*)d_in[16];

    char* ws = (char*)d_ws;
    size_t off = 0;
    auto alloc = [&](size_t bytes) { char* q = ws + off; off += (bytes + 255) & ~(size_t)255; return q; };
    p.so_bf   = (u16*)alloc((size_t)B_ROWS * D0 * 2);
    p.partial = (float*)alloc((size_t)B_ROWS * 4);
    p.W1T     = (u16*)alloc((size_t)H1 * D0 * 2);
    p.W2T     = (u16*)alloc((size_t)H2 * H1 * 2);
    p.W2s     = (u16*)alloc((size_t)H2 * H1 * 2);
    p.psum1   = (float*)alloc((size_t)256 * H1 * 4);
    p.psq1    = (float*)alloc((size_t)256 * H1 * 4);
    p.psum2   = (float*)alloc((size_t)256 * H2 * 4);
    p.psq2    = (float*)alloc((size_t)256 * H2 * 4);
    p.a1      = (float*)alloc(H1 * 4);
    p.a2      = (float*)alloc(H2 * 4);
    p.c2      = (float*)alloc(H2 * 4);
    p.Z1bf    = (u16*)alloc((size_t)B_ROWS * H1 * 2);
    p.Z2bf    = (u16*)alloc((size_t)B_ROWS * H2 * 2);
    p.out     = (float*)d_out;
    (void)in_sizes; (void)n_in; (void)out_size; (void)ws_size;

    embed_prep_k<<<1024, 256, 0, stream>>>(p);
    gemm1_k    <<<512, 256, 0, stream>>>(p);
    finstats1_k<<<64, 256, 0, stream>>>(p);
    gemm2_k    <<<512, 256, 0, stream>>>(p);
    finstats2_k<<<32, 256, 0, stream>>>(p);
    final_k    <<<B_ROWS / 4, 256, 0, stream>>>(p);
}

// Round 16
// 74.528 us; speedup vs baseline: 1.0252x; 1.0252x over previous
//
#include <hip/hip_runtime.h>

// ---------------------------------------------------------------------------
// DeepFM forward, MI355X. Round 16: unbundle R15.
//  - gemm1: reverted to R14's exact proven form (3-buffer, vmcnt(4), BK=32,
//    T2 swizzle) — R15's 4-buffer cost occupancy 3->2 blocks/CU, regressed.
//  - gemm2: full-async A+B template, 3 buffers (36KB -> 4 blocks/CU),
//    depth-2 counted vmcnt(3); removes R14-gemm2's per-iter vmcnt(0) drain.
//  - finstats1: W2s[n][k] = W2T[n][k]*a1[k] prescale (enables async B).
// Embed: R14. Algebra: b1/bt1/b2 cancel; BN1 = diag(a1) via W2s.
// ---------------------------------------------------------------------------

#define B_ROWS 16384
#define VOCAB 100000
#define D0 640
#define H1 512
#define H2 256
#define EPSV 1e-5f

typedef short bf16x8 __attribute__((ext_vector_type(8)));
typedef float f32x4 __attribute__((ext_vector_type(4)));
typedef unsigned short u16;

struct Params {
    const int* Xi; const float* Xv; const float* bias;
    const float* dw1; const float* db1; const float* e1;
    const float* dw2; const float* db2; const float* e2;
    const float* W1; const float* g1; const float* bt1;
    const float* W2; const float* g2; const float* bt2;
    u16* so_bf; float* partial; u16* W1T; u16* W2T; u16* W2s;
    float* psum1; float* psq1; float* psum2; float* psq2;
    float* a1; float* a2; float* c2;
    u16* Z1bf; u16* Z2bf; float* out;
};

__device__ inline u16 f2bf(float x) {
    unsigned u = __float_as_uint(x);
    return (u16)((u + 0x7fffu + ((u >> 16) & 1u)) >> 16);   // RNE
}
__device__ inline float bf2f(unsigned b) {
    return __uint_as_float((b & 0xffffu) << 16);
}
__device__ inline void async16(const void* g, void* l) {
    __builtin_amdgcn_global_load_lds(
        (const __attribute__((address_space(1))) void*)g,
        (__attribute__((address_space(3))) void*)l, 16, 0, 0);
}

// ---------------------------------------------------------------------------
// K1: fused weight transposes (blocks 0..447) + embed/FM. (== R14)
__global__ __launch_bounds__(256) void embed_prep_k(Params p) {
    __shared__ float tile[32][33];
    __shared__ u16 so_lds[16][648];                  // +8 pad
    __shared__ __align__(16) int   xi_lds[16][40];
    __shared__ __align__(16) float xv_lds[16][40];
    __shared__ __align__(16) float w_lds[4][208];    // dw1,db1,dw2,db2
    const int bid = blockIdx.x, tid = threadIdx.x;
    const int rblk = (bid & 7) * 128 + (bid >> 3);   // XCD-aligned row-group

    if (tid < 160) {
        ((uint4*)&xi_lds[0][0])[tid] = ((const uint4*)(p.Xi + (size_t)rblk * 16 * 40))[tid];
        ((uint4*)&xv_lds[0][0])[tid] = ((const uint4*)(p.Xv + (size_t)rblk * 16 * 40))[tid];
    }
    if (tid < 52)        ((uint4*)&w_lds[0][0])[tid]       = ((const uint4*)p.dw1)[tid];
    else if (tid < 104)  ((uint4*)&w_lds[1][0])[tid - 52]  = ((const uint4*)p.db1)[tid - 52];
    else if (tid < 156)  ((uint4*)&w_lds[2][0])[tid - 104] = ((const uint4*)p.dw2)[tid - 104];
    else if (tid < 208)  ((uint4*)&w_lds[3][0])[tid - 156] = ((const uint4*)p.db2)[tid - 156];

    if (bid < 448) {            // transpose W1 (320 tiles) / W2 (128 tiles)
        const float* W; u16* WT; int K, N, k0, n0;
        if (bid < 320) { W = p.W1; WT = p.W1T; K = D0; N = H1; k0 = (bid % 20) * 32; n0 = (bid / 20) * 32; }
        else { int b2 = bid - 320; W = p.W2; WT = p.W2T; K = H1; N = H2; k0 = (b2 % 16) * 32; n0 = (b2 / 16) * 32; }
        int tx = tid & 31, ty4 = (tid >> 5) * 4;
#pragma unroll
        for (int r = 0; r < 4; ++r)
            tile[ty4 + r][tx] = W[(size_t)(k0 + ty4 + r) * N + n0 + tx];
        __syncthreads();
#pragma unroll
        for (int r = 0; r < 4; ++r)
            WT[(size_t)(n0 + ty4 + r) * K + k0 + tx] = f2bf(tile[tx][ty4 + r]);
    }
    __syncthreads();

    const int e = tid & 15;
    const int r = tid >> 4;
    const int b = rblk * 16 + r;

    float accf = 0.f, s1 = 0.f, sq = 0.f;
#pragma unroll
    for (int f = 0; f < 13; ++f) {
        float x = (float)xi_lds[r][f];
        float xv = xv_lds[r][f];
        float fo = (x * w_lds[0][f * 16 + e] + w_lds[1][f * 16 + e]) * xv;
        float so = (x * w_lds[2][f * 16 + e] + w_lds[3][f * 16 + e]) * xv;
        accf += fo; s1 += so; sq += so * so;
        so_lds[r][f * 16 + e] = f2bf(so);
    }
#pragma unroll 1
    for (int c = 0; c < 3; ++c) {
        const int base = 13 + c * 9;
        int   ix[9]; float xv9[9], v1[9], v2[9];
#pragma unroll
        for (int s = 0; s < 9; ++s) { ix[s] = xi_lds[r][base + s]; xv9[s] = xv_lds[r][base + s]; }
#pragma unroll
        for (int s = 0; s < 9; ++s) {
            size_t off = (size_t)(base - 13 + s) * (VOCAB * 16) + (size_t)ix[s] * 16 + e;
            v1[s] = p.e1[off];
            v2[s] = p.e2[off];
        }
#pragma unroll
        for (int s = 0; s < 9; ++s) {
            float fo = v1[s] * xv9[s], so = v2[s] * xv9[s];
            accf += fo; s1 += so; sq += so * so;
            so_lds[r][(base + s) * 16 + e] = f2bf(so);
        }
    }
    float val = accf + 0.5f * (s1 * s1 - sq);
    val += __shfl_xor(val, 1); val += __shfl_xor(val, 2);
    val += __shfl_xor(val, 4); val += __shfl_xor(val, 8);
    if (e == 0) p.partial[b] = val + p.bias[b];

    __syncthreads();
    uint4* gdst = (uint4*)(p.so_bf + (size_t)rblk * 16 * D0);
#pragma unroll
    for (int k = 0; k < 5; ++k) {
        int v = k * 256 + tid;
        int row = v / 80, c16 = v - row * 80;
        gdst[v] = *(const uint4*)&so_lds[row][c16 * 8];
    }
}

// ---------------------------------------------------------------------------
// K2: Z1 = so @ W1T^T (NT). 128x128 tile, BK=32, 3-buffer counted-vmcnt(4)
// + T2 swizzle. Fused column stats. (== R14 exact)
__global__ __launch_bounds__(256) void gemm1_k(Params p) {
    __shared__ u16 As[3][128 * 32];
    __shared__ u16 Bs[3][128 * 32];
    const int tid = threadIdx.x, lane = tid & 63, w = tid >> 6;
    const int bid = (int)blockIdx.x;
    const int g = bid >> 3, x = bid & 7;
    const int mt = x * 16 + (g >> 2), nt = g & 3;
    const int m0 = mt * 128, n0 = nt * 128;
    const int wr = w >> 1, wc = w & 1;

    f32x4 acc[4][4] = {};

    auto stage = [&](int buf, int kt) {
#pragma unroll
        for (int j = 0; j < 2; ++j) {
            int s = j * 256 + tid;
            int row = s >> 2;
            int c8 = ((s ^ (s >> 3)) & 3) * 8;
            async16(p.so_bf + (size_t)(m0 + row) * D0 + kt + c8,
                    &As[buf][(j * 256 + w * 64) * 8]);
            async16(p.W1T + (size_t)(n0 + row) * D0 + kt + c8,
                    &Bs[buf][(j * 256 + w * 64) * 8]);
        }
    };

    const int NT = D0 / 32;                     // 20
    stage(0, 0);
    stage(1, 32);
    for (int t = 0; t < NT; ++t) {
        if (t < NT - 1) asm volatile("s_waitcnt vmcnt(4)" ::: "memory");
        else            asm volatile("s_waitcnt vmcnt(0)" ::: "memory");
        __builtin_amdgcn_s_barrier();
        __builtin_amdgcn_sched_barrier(0);
        if (t + 2 < NT) stage((t + 2) % 3, (t + 2) * 32);
        const u16* Ac = As[t % 3];
        const u16* Bc = Bs[t % 3];
        const int gq = lane >> 4;
        bf16x8 af[4], bfr[4];
#pragma unroll
        for (int i = 0; i < 4; ++i) {
            int ar = wr * 64 + i * 16 + (lane & 15);
            af[i] = *(const bf16x8*)&Ac[ar * 32 + ((gq ^ ((ar >> 1) & 3)) * 8)];
            int br = wc * 64 + i * 16 + (lane & 15);
            bfr[i] = *(const bf16x8*)&Bc[br * 32 + ((gq ^ ((br >> 1) & 3)) * 8)];
        }
#pragma unroll
        for (int i = 0; i < 4; ++i)
#pragma unroll
            for (int j2 = 0; j2 < 4; ++j2)
                acc[i][j2] = __builtin_amdgcn_mfma_f32_16x16x32_bf16(
                    af[i], bfr[j2], acc[i][j2], 0, 0, 0);
    }
#pragma unroll
    for (int i = 0; i < 4; ++i)
#pragma unroll
        for (int j2 = 0; j2 < 4; ++j2) {
            int row = m0 + wr * 64 + i * 16 + (lane >> 4) * 4;
            int col = n0 + wc * 64 + j2 * 16 + (lane & 15);
#pragma unroll
            for (int q = 0; q < 4; ++q)
                p.Z1bf[(size_t)(row + q) * H1 + col] = f2bf(acc[i][j2][q]);
        }
    const int chunk = mt * 2 + wr;               // 256 chunks
#pragma unroll
    for (int j2 = 0; j2 < 4; ++j2) {
        float s = 0.f, q = 0.f;
#pragma unroll
        for (int i = 0; i < 4; ++i)
#pragma unroll
            for (int qq = 0; qq < 4; ++qq) { float v = acc[i][j2][qq]; s += v; q += v * v; }
        s += __shfl_xor(s, 16); s += __shfl_xor(s, 32);
        q += __shfl_xor(q, 16); q += __shfl_xor(q, 32);
        if (lane < 16) {
            int col = n0 + wc * 64 + j2 * 16 + lane;
            p.psum1[(size_t)chunk * H1 + col] = s;
            p.psq1[(size_t)chunk * H1 + col] = q;
        }
    }
}

// ---------------------------------------------------------------------------
// K3: a1 + W2s prescale. 64 blocks, 32 lanes/col, tree reduce; each lane
// group then scales its column of W2T.
__global__ __launch_bounds__(256) void finstats1_k(Params p) {
    int col = blockIdx.x * 8 + (threadIdx.x >> 5);
    int l32 = threadIdx.x & 31;
    float s = 0.f, q = 0.f;
#pragma unroll
    for (int k = 0; k < 8; ++k) {
        int ch = k * 32 + l32;
        s += p.psum1[(size_t)ch * H1 + col];
        q += p.psq1[(size_t)ch * H1 + col];
    }
#pragma unroll
    for (int m = 1; m <= 16; m <<= 1) {
        s += __shfl_xor(s, m);
        q += __shfl_xor(q, m);
    }
    const float inv = 1.0f / (float)B_ROWS;
    float mean = s * inv;
    float var = q * inv - mean * mean;
    float av = p.g1[col] * rsqrtf(var + EPSV);
    if (l32 == 0) p.a1[col] = av;
#pragma unroll
    for (int k = 0; k < 8; ++k) {
        int n = k * 32 + l32;
        p.W2s[(size_t)n * H1 + col] = f2bf(bf2f(p.W2T[(size_t)n * H1 + col]) * av);
    }
}

// ---------------------------------------------------------------------------
// K4: Z2 = Z1 @ W2s^T (NT). 128x64 tile, BK=32, 3-buffer depth-2 counted
// vmcnt(3) + T2 swizzle — full-async A and B (gemm1's template).
__global__ __launch_bounds__(256) void gemm2_k(Params p) {
    __shared__ u16 As[3][128 * 32];
    __shared__ u16 Bs[3][64 * 32];
    const int tid = threadIdx.x, lane = tid & 63, w = tid >> 6;
    const int bid = (int)blockIdx.x;
    const int g = bid >> 3, x = bid & 7;
    const int mt = x * 16 + (g >> 2), nt = g & 3;
    const int m0 = mt * 128, n0 = nt * 64;
    const int wr = w >> 1, wc = w & 1;

    f32x4 acc[4][2] = {};

    auto stage = [&](int buf, int kt) {         // 3 asyncs/thread
#pragma unroll
        for (int j = 0; j < 2; ++j) {
            int s = j * 256 + tid;
            int row = s >> 2;
            int c8 = ((s ^ (s >> 3)) & 3) * 8;
            async16(p.Z1bf + (size_t)(m0 + row) * H1 + kt + c8,
                    &As[buf][(j * 256 + w * 64) * 8]);
        }
        {
            int s = tid;
            int row = s >> 2;
            int c8 = ((s ^ (s >> 3)) & 3) * 8;
            async16(p.W2s + (size_t)(n0 + row) * H1 + kt + c8,
                    &Bs[buf][(w * 64) * 8]);
        }
    };

    const int NT = H1 / 32;                     // 16
    stage(0, 0);
    stage(1, 32);
    for (int t = 0; t < NT; ++t) {
        if (t < NT - 1) asm volatile("s_waitcnt vmcnt(3)" ::: "memory");
        else            asm volatile("s_waitcnt vmcnt(0)" ::: "memory");
        __builtin_amdgcn_s_barrier();
        __builtin_amdgcn_sched_barrier(0);
        if (t + 2 < NT) stage((t + 2) % 3, (t + 2) * 32);
        const u16* Ac = As[t % 3];
        const u16* Bc = Bs[t % 3];
        const int gq = lane >> 4;
        bf16x8 af[4], bfr[2];
#pragma unroll
        for (int i = 0; i < 4; ++i) {
            int ar = wr * 64 + i * 16 + (lane & 15);
            af[i] = *(const bf16x8*)&Ac[ar * 32 + ((gq ^ ((ar >> 1) & 3)) * 8)];
        }
#pragma unroll
        for (int j2 = 0; j2 < 2; ++j2) {
            int br = wc * 32 + j2 * 16 + (lane & 15);
            bfr[j2] = *(const bf16x8*)&Bc[br * 32 + ((gq ^ ((br >> 1) & 3)) * 8)];
        }
#pragma unroll
        for (int i = 0; i < 4; ++i)
#pragma unroll
            for (int j2 = 0; j2 < 2; ++j2)
                acc[i][j2] = __builtin_amdgcn_mfma_f32_16x16x32_bf16(
                    af[i], bfr[j2], acc[i][j2], 0, 0, 0);
    }
#pragma unroll
    for (int i = 0; i < 4; ++i)
#pragma unroll
        for (int j2 = 0; j2 < 2; ++j2) {
            int row = m0 + wr * 64 + i * 16 + (lane >> 4) * 4;
            int col = n0 + wc * 32 + j2 * 16 + (lane & 15);
#pragma unroll
            for (int q = 0; q < 4; ++q)
                p.Z2bf[(size_t)(row + q) * H2 + col] = f2bf(acc[i][j2][q]);
        }
    const int chunk = mt * 2 + wr;               // 256 chunks
#pragma unroll
    for (int j2 = 0; j2 < 2; ++j2) {
        float s = 0.f, q = 0.f;
#pragma unroll
        for (int i = 0; i < 4; ++i)
#pragma unroll
            for (int qq = 0; qq < 4; ++qq) { float v = acc[i][j2][qq]; s += v; q += v * v; }
        s += __shfl_xor(s, 16); s += __shfl_xor(s, 32);
        q += __shfl_xor(q, 16); q += __shfl_xor(q, 32);
        if (lane < 16) {
            int col = n0 + wc * 32 + j2 * 16 + lane;
            p.psum2[(size_t)chunk * H2 + col] = s;
            p.psq2[(size_t)chunk * H2 + col] = q;
        }
    }
}

// ---------------------------------------------------------------------------
// K5: a2,c2. 32 blocks, 32 lanes/col, tree reduce. (== R14)
__global__ __launch_bounds__(256) void finstats2_k(Params p) {
    int col = blockIdx.x * 8 + (threadIdx.x >> 5);
    int l32 = threadIdx.x & 31;
    float s = 0.f, q = 0.f;
#pragma unroll
    for (int k = 0; k < 8; ++k) {
        int ch = k * 32 + l32;
        s += p.psum2[(size_t)ch * H2 + col];
        q += p.psq2[(size_t)ch * H2 + col];
    }
#pragma unroll
    for (int m = 1; m <= 16; m <<= 1) {
        s += __shfl_xor(s, m);
        q += __shfl_xor(q, m);
    }
    if (l32 == 0) {
        const float inv = 1.0f / (float)B_ROWS;
        float mean = s * inv;
        float var = q * inv - mean * mean;
        float av = p.g2[col] * rsqrtf(var + EPSV);
        p.a2[col] = av;
        p.c2[col] = p.bt2[col] - mean * av;
    }
}

// ---------------------------------------------------------------------------
// K6: out[b] = partial[b] + sum_c (Z2[b,c]*a2[c] + c2[c]). XCD-chained. (==R14)
__global__ __launch_bounds__(256) void final_k(Params p) {
    int w = threadIdx.x >> 6, lane = threadIdx.x & 63;
    int j = (int)blockIdx.x;
    int gblk = (j & 7) * 512 + (j >> 3);
    int b = gblk * 4 + w;
    ushort4 z4 = *(const ushort4*)(p.Z2bf + (size_t)b * H2 + lane * 4);
    float4 a = *(const float4*)(p.a2 + lane * 4);
    float4 c = *(const float4*)(p.c2 + lane * 4);
    float v = bf2f(z4.x) * a.x + c.x + bf2f(z4.y) * a.y + c.y
            + bf2f(z4.z) * a.z + c.z + bf2f(z4.w) * a.w + c.w;
#pragma unroll
    for (int m = 1; m < 64; m <<= 1) v += __shfl_xor(v, m);
    if (lane == 0) p.out[b] = p.partial[b] + v;
}

// ---------------------------------------------------------------------------
extern "C" void kernel_launch(void* const* d_in, const int* in_sizes, int n_in,
                              void* d_out, int out_size, void* d_ws, size_t ws_size,
                              hipStream_t stream)
{
    Params p;
    p.Xi   = (const int*)d_in[0];
    p.Xv   = (const float*)d_in[1];
    p.bias = (const float*)d_in[2];
    p.dw1  = (const float*)d_in[3];
    p.db1  = (const float*)d_in[4];
    p.e1   = (const float*)d_in[5];
    p.dw2  = (const float*)d_in[6];
    p.db2  = (const float*)d_in[7];
    p.e2   = (const float*)d_in[8];
    p.W1   = (const float*)d_in[9];
    // d_in[10] = b1: cancels in BN1 -> unused
    p.g1   = (const float*)d_in[11];
    p.bt1  = (const float*)d_in[12];   // col-const shift -> cancels in BN2 -> unused
    p.W2   = (const float*)d_in[13];
    // d_in[14] = b2: cancels in BN2 -> unused
    p.g2   = (const float*)d_in[15];
    p.bt2  = (const float*)d_in[16];

    char* ws = (char*)d_ws;
    size_t off = 0;
    auto alloc = [&](size_t bytes) { char* q = ws + off; off += (bytes + 255) & ~(size_t)255; return q; };
    p.so_bf   = (u16*)alloc((size_t)B_ROWS * D0 * 2);
    p.partial = (float*)alloc((size_t)B_ROWS * 4);
    p.W1T     = (u16*)alloc((size_t)H1 * D0 * 2);
    p.W2T     = (u16*)alloc((size_t)H2 * H1 * 2);
    p.W2s     = (u16*)alloc((size_t)H2 * H1 * 2);
    p.psum1   = (float*)alloc((size_t)256 * H1 * 4);
    p.psq1    = (float*)alloc((size_t)256 * H1 * 4);
    p.psum2   = (float*)alloc((size_t)256 * H2 * 4);
    p.psq2    = (float*)alloc((size_t)256 * H2 * 4);
    p.a1      = (float*)alloc(H1 * 4);
    p.a2      = (float*)alloc(H2 * 4);
    p.c2      = (float*)alloc(H2 * 4);
    p.Z1bf    = (u16*)alloc((size_t)B_ROWS * H1 * 2);
    p.Z2bf    = (u16*)alloc((size_t)B_ROWS * H2 * 2);
    p.out     = (float*)d_out;
    (void)in_sizes; (void)n_in; (void)out_size; (void)ws_size;

    embed_prep_k<<<1024, 256, 0, stream>>>(p);
    gemm1_k    <<<512, 256, 0, stream>>>(p);
    finstats1_k<<<64, 256, 0, stream>>>(p);
    gemm2_k    <<<512, 256, 0, stream>>>(p);
    finstats2_k<<<32, 256, 0, stream>>>(p);
    final_k    <<<B_ROWS / 4, 256, 0, stream>>>(p);
}

// Round 17
// 73.676 us; speedup vs baseline: 1.0371x; 1.0116x over previous
//
#include <hip/hip_runtime.h>

// ---------------------------------------------------------------------------
// DeepFM forward, MI355X. Round 17: lock-in of R14 (measured best, 73.78us).
// Pipeline: embed_prep (transposes + LDS-staged embed/FM, XCD-aligned rows)
//   -> gemm1 (128x128, BK=32, 3-buf counted-vmcnt(4), T2 swizzle, fused stats)
//   -> finstats1 (32 lanes/col tree) -> gemm2 (128x64, BK=64, reg-staged
//   a1-folded B, T2 swizzle) -> finstats2 -> final (XCD-chained).
// Algebra: b1/bt1/b2 cancel in BN; BN1 folded as diag(a1) into gemm2's B.
// Established floors: embed at random-gather line-traffic floor (~22us,
// R10/R12/R13 probes); GEMM levers measured null/regressive beyond this
// config; fusion poisoned by 8-XCD fence cost (R3/R7).
// ---------------------------------------------------------------------------

#define B_ROWS 16384
#define VOCAB 100000
#define D0 640
#define H1 512
#define H2 256
#define EPSV 1e-5f

typedef short bf16x8 __attribute__((ext_vector_type(8)));
typedef float f32x4 __attribute__((ext_vector_type(4)));
typedef unsigned short u16;

struct Params {
    const int* Xi; const float* Xv; const float* bias;
    const float* dw1; const float* db1; const float* e1;
    const float* dw2; const float* db2; const float* e2;
    const float* W1; const float* g1; const float* bt1;
    const float* W2; const float* g2; const float* bt2;
    u16* so_bf; float* partial; u16* W1T; u16* W2T;
    float* psum1; float* psq1; float* psum2; float* psq2;
    float* a1; float* a2; float* c2;
    u16* Z1bf; u16* Z2bf; float* out;
};

__device__ inline u16 f2bf(float x) {
    unsigned u = __float_as_uint(x);
    return (u16)((u + 0x7fffu + ((u >> 16) & 1u)) >> 16);   // RNE
}
__device__ inline float bf2f(unsigned b) {
    return __uint_as_float((b & 0xffffu) << 16);
}
__device__ inline void async16(const void* g, void* l) {
    __builtin_amdgcn_global_load_lds(
        (const __attribute__((address_space(1))) void*)g,
        (__attribute__((address_space(3))) void*)l, 16, 0, 0);
}

// ---------------------------------------------------------------------------
// K1: fused weight transposes (blocks 0..447) + embed/FM.
__global__ __launch_bounds__(256) void embed_prep_k(Params p) {
    __shared__ float tile[32][33];
    __shared__ u16 so_lds[16][648];                  // +8 pad
    __shared__ __align__(16) int   xi_lds[16][40];
    __shared__ __align__(16) float xv_lds[16][40];
    __shared__ __align__(16) float w_lds[4][208];    // dw1,db1,dw2,db2
    const int bid = blockIdx.x, tid = threadIdx.x;
    const int rblk = (bid & 7) * 128 + (bid >> 3);   // XCD-aligned row-group

    // ---- coalesced staging ----
    if (tid < 160) {
        ((uint4*)&xi_lds[0][0])[tid] = ((const uint4*)(p.Xi + (size_t)rblk * 16 * 40))[tid];
        ((uint4*)&xv_lds[0][0])[tid] = ((const uint4*)(p.Xv + (size_t)rblk * 16 * 40))[tid];
    }
    if (tid < 52)        ((uint4*)&w_lds[0][0])[tid]       = ((const uint4*)p.dw1)[tid];
    else if (tid < 104)  ((uint4*)&w_lds[1][0])[tid - 52]  = ((const uint4*)p.db1)[tid - 52];
    else if (tid < 156)  ((uint4*)&w_lds[2][0])[tid - 104] = ((const uint4*)p.dw2)[tid - 104];
    else if (tid < 208)  ((uint4*)&w_lds[3][0])[tid - 156] = ((const uint4*)p.db2)[tid - 156];

    if (bid < 448) {            // transpose W1 (320 tiles) / W2 (128 tiles)
        const float* W; u16* WT; int K, N, k0, n0;
        if (bid < 320) { W = p.W1; WT = p.W1T; K = D0; N = H1; k0 = (bid % 20) * 32; n0 = (bid / 20) * 32; }
        else { int b2 = bid - 320; W = p.W2; WT = p.W2T; K = H1; N = H2; k0 = (b2 % 16) * 32; n0 = (b2 / 16) * 32; }
        int tx = tid & 31, ty4 = (tid >> 5) * 4;
#pragma unroll
        for (int r = 0; r < 4; ++r)
            tile[ty4 + r][tx] = W[(size_t)(k0 + ty4 + r) * N + n0 + tx];
        __syncthreads();
#pragma unroll
        for (int r = 0; r < 4; ++r)
            WT[(size_t)(n0 + ty4 + r) * K + k0 + tx] = f2bf(tile[tx][ty4 + r]);
    }
    __syncthreads();                                 // staging visible to all

    // ---- embed: 16 rows/block, 16 lanes/row ----
    const int e = tid & 15;
    const int r = tid >> 4;
    const int b = rblk * 16 + r;

    float accf = 0.f, s1 = 0.f, sq = 0.f;
#pragma unroll
    for (int f = 0; f < 13; ++f) {
        float x = (float)xi_lds[r][f];
        float xv = xv_lds[r][f];
        float fo = (x * w_lds[0][f * 16 + e] + w_lds[1][f * 16 + e]) * xv;
        float so = (x * w_lds[2][f * 16 + e] + w_lds[3][f * 16 + e]) * xv;
        accf += fo; s1 += so; sq += so * so;
        so_lds[r][f * 16 + e] = f2bf(so);
    }
    // gathers: 3 x 9 chunks, indices/values from LDS
#pragma unroll 1
    for (int c = 0; c < 3; ++c) {
        const int base = 13 + c * 9;
        int   ix[9]; float xv9[9], v1[9], v2[9];
#pragma unroll
        for (int s = 0; s < 9; ++s) { ix[s] = xi_lds[r][base + s]; xv9[s] = xv_lds[r][base + s]; }
#pragma unroll
        for (int s = 0; s < 9; ++s) {
            size_t off = (size_t)(base - 13 + s) * (VOCAB * 16) + (size_t)ix[s] * 16 + e;
            v1[s] = p.e1[off];
            v2[s] = p.e2[off];
        }
#pragma unroll
        for (int s = 0; s < 9; ++s) {
            float fo = v1[s] * xv9[s], so = v2[s] * xv9[s];
            accf += fo; s1 += so; sq += so * so;
            so_lds[r][(base + s) * 16 + e] = f2bf(so);
        }
    }
    float val = accf + 0.5f * (s1 * s1 - sq);
    val += __shfl_xor(val, 1); val += __shfl_xor(val, 2);
    val += __shfl_xor(val, 4); val += __shfl_xor(val, 8);
    if (e == 0) p.partial[b] = val + p.bias[b];

    __syncthreads();
    uint4* gdst = (uint4*)(p.so_bf + (size_t)rblk * 16 * D0);
#pragma unroll
    for (int k = 0; k < 5; ++k) {
        int v = k * 256 + tid;                 // 0..1279
        int row = v / 80, c16 = v - row * 80;  // 80 uint4 per row
        gdst[v] = *(const uint4*)&so_lds[row][c16 * 8];
    }
}

// ---------------------------------------------------------------------------
// K2: Z1 = so @ W1T^T (NT). 128x128 tile, BK=32, 3-buffer counted-vmcnt
// pipeline + T2 swizzle (slot ^= (row>>1)&3; src pre-swizzled, LDS linear).
__global__ __launch_bounds__(256) void gemm1_k(Params p) {
    __shared__ u16 As[3][128 * 32];
    __shared__ u16 Bs[3][128 * 32];
    const int tid = threadIdx.x, lane = tid & 63, w = tid >> 6;
    const int bid = (int)blockIdx.x;
    const int g = bid >> 3, x = bid & 7;
    const int mt = x * 16 + (g >> 2), nt = g & 3;     // 128 m-tiles, 4 n-tiles
    const int m0 = mt * 128, n0 = nt * 128;
    const int wr = w >> 1, wc = w & 1;

    f32x4 acc[4][4] = {};

    auto stage = [&](int buf, int kt) {
#pragma unroll
        for (int j = 0; j < 2; ++j) {
            int s = j * 256 + tid;              // 16B slot id (row = s>>2)
            int row = s >> 2;
            int c8 = ((s ^ (s >> 3)) & 3) * 8;  // (slot) ^ ((row>>1)&3)
            async16(p.so_bf + (size_t)(m0 + row) * D0 + kt + c8,
                    &As[buf][(j * 256 + w * 64) * 8]);
            async16(p.W1T + (size_t)(n0 + row) * D0 + kt + c8,
                    &Bs[buf][(j * 256 + w * 64) * 8]);
        }
    };

    const int NT = D0 / 32;                     // 20
    stage(0, 0);
    stage(1, 32);
    for (int t = 0; t < NT; ++t) {
        if (t < NT - 1) asm volatile("s_waitcnt vmcnt(4)" ::: "memory");
        else            asm volatile("s_waitcnt vmcnt(0)" ::: "memory");
        __builtin_amdgcn_s_barrier();
        __builtin_amdgcn_sched_barrier(0);
        if (t + 2 < NT) stage((t + 2) % 3, (t + 2) * 32);
        const u16* Ac = As[t % 3];
        const u16* Bc = Bs[t % 3];
        const int gq = lane >> 4;               // k-slot group 0..3
        bf16x8 af[4], bfr[4];
#pragma unroll
        for (int i = 0; i < 4; ++i) {
            int ar = wr * 64 + i * 16 + (lane & 15);
            af[i] = *(const bf16x8*)&Ac[ar * 32 + ((gq ^ ((ar >> 1) & 3)) * 8)];
            int br = wc * 64 + i * 16 + (lane & 15);
            bfr[i] = *(const bf16x8*)&Bc[br * 32 + ((gq ^ ((br >> 1) & 3)) * 8)];
        }
#pragma unroll
        for (int i = 0; i < 4; ++i)
#pragma unroll
            for (int j2 = 0; j2 < 4; ++j2)
                acc[i][j2] = __builtin_amdgcn_mfma_f32_16x16x32_bf16(
                    af[i], bfr[j2], acc[i][j2], 0, 0, 0);
    }
#pragma unroll
    for (int i = 0; i < 4; ++i)
#pragma unroll
        for (int j2 = 0; j2 < 4; ++j2) {
            int row = m0 + wr * 64 + i * 16 + (lane >> 4) * 4;
            int col = n0 + wc * 64 + j2 * 16 + (lane & 15);
#pragma unroll
            for (int q = 0; q < 4; ++q)
                p.Z1bf[(size_t)(row + q) * H1 + col] = f2bf(acc[i][j2][q]);
        }
    const int chunk = mt * 2 + wr;               // 256 chunks
#pragma unroll
    for (int j2 = 0; j2 < 4; ++j2) {
        float s = 0.f, q = 0.f;
#pragma unroll
        for (int i = 0; i < 4; ++i)
#pragma unroll
            for (int qq = 0; qq < 4; ++qq) { float v = acc[i][j2][qq]; s += v; q += v * v; }
        s += __shfl_xor(s, 16); s += __shfl_xor(s, 32);
        q += __shfl_xor(q, 16); q += __shfl_xor(q, 32);
        if (lane < 16) {
            int col = n0 + wc * 64 + j2 * 16 + lane;
            p.psum1[(size_t)chunk * H1 + col] = s;
            p.psq1[(size_t)chunk * H1 + col] = q;
        }
    }
}

// ---------------------------------------------------------------------------
// K3: a1[col] = g1 * rsqrt(var+eps). 64 blocks, 32 lanes/col, tree reduce.
__global__ __launch_bounds__(256) void finstats1_k(Params p) {
    int col = blockIdx.x * 8 + (threadIdx.x >> 5);
    int l32 = threadIdx.x & 31;
    float s = 0.f, q = 0.f;
#pragma unroll
    for (int k = 0; k < 8; ++k) {
        int ch = k * 32 + l32;
        s += p.psum1[(size_t)ch * H1 + col];
        q += p.psq1[(size_t)ch * H1 + col];
    }
#pragma unroll
    for (int m = 1; m <= 16; m <<= 1) {
        s += __shfl_xor(s, m);
        q += __shfl_xor(q, m);
    }
    if (l32 == 0) {
        const float inv = 1.0f / (float)B_ROWS;
        float mean = s * inv;
        float var = q * inv - mean * mean;
        p.a1[col] = p.g1[col] * rsqrtf(var + EPSV);
    }
}

// ---------------------------------------------------------------------------
// K4: Z2 = Z1 * diag(a1) * W2 (a1 folded into reg-staged B). 128x64 tile,
// BK=64 + T2 swizzle (slot ^= row&7) on A (pre-swizzled src) and B
// (ds_write addr swizzled).
__global__ __launch_bounds__(256) void gemm2_k(Params p) {
    __shared__ u16 As[2][128 * 64];
    __shared__ u16 Bs[2][64 * 64];
    const int tid = threadIdx.x, lane = tid & 63, w = tid >> 6;
    const int bid = (int)blockIdx.x;
    const int g = bid >> 3, x = bid & 7;
    const int mt = x * 16 + (g >> 2), nt = g & 3;     // 128 m-tiles, 4 n-tiles
    const int m0 = mt * 128, n0 = nt * 64;
    const int wr = w >> 1, wc = w & 1;
    const int srow = lane >> 3;
    const int scol_sw = ((lane ^ (lane >> 3)) & 7) * 8;

    f32x4 acc[4][2] = {};

    auto stageA = [&](int buf, int kt) {
#pragma unroll
        for (int j = 0; j < 4; ++j) {
            int r0 = w * 32 + j * 8;
            async16(p.Z1bf + (size_t)(m0 + r0 + srow) * H1 + kt + scol_sw,
                    &As[buf][r0 * 64]);
        }
    };
    auto loadB = [&](uint4* br, int kt) {
#pragma unroll
        for (int r = 0; r < 2; ++r) {
            int li = r * 256 + tid, row = li >> 3, c8 = (li & 7) * 8;
            br[r] = *(const uint4*)(p.W2T + (size_t)(n0 + row) * H1 + kt + c8);
        }
    };
    auto writeB = [&](int buf, const uint4* br, int kt) {
#pragma unroll
        for (int r = 0; r < 2; ++r) {
            int li = r * 256 + tid, row = li >> 3, c8 = (li & 7) * 8;
            float4 alo = *(const float4*)(p.a1 + kt + c8);
            float4 ahi = *(const float4*)(p.a1 + kt + c8 + 4);
            uint4 z = br[r];
            uint4 o;
            o.x = (unsigned)f2bf(bf2f(z.x) * alo.x) | ((unsigned)f2bf(bf2f(z.x >> 16) * alo.y) << 16);
            o.y = (unsigned)f2bf(bf2f(z.y) * alo.z) | ((unsigned)f2bf(bf2f(z.y >> 16) * alo.w) << 16);
            o.z = (unsigned)f2bf(bf2f(z.z) * ahi.x) | ((unsigned)f2bf(bf2f(z.z >> 16) * ahi.y) << 16);
            o.w = (unsigned)f2bf(bf2f(z.w) * ahi.z) | ((unsigned)f2bf(bf2f(z.w >> 16) * ahi.w) << 16);
            int csw = ((li ^ (li >> 3)) & 7) * 8;
            *(uint4*)&Bs[buf][row * 64 + csw] = o;
        }
    };

    uint4 breg[2];
    stageA(0, 0);
    loadB(breg, 0);
    writeB(0, breg, 0);
    __syncthreads();
    int cur = 0;
    for (int t = 0; t < 8; ++t) {
        uint4 bnx[2];
        if (t < 7) { stageA(cur ^ 1, (t + 1) * 64); loadB(bnx, (t + 1) * 64); }
#pragma unroll
        for (int kk = 0; kk < 2; ++kk) {
            bf16x8 af[4], bfr[2];
#pragma unroll
            for (int i = 0; i < 4; ++i) {
                int ar = wr * 64 + i * 16 + (lane & 15);
                int gq = kk * 4 + (lane >> 4);
                af[i] = *(const bf16x8*)&As[cur][ar * 64 + ((gq ^ (ar & 7)) * 8)];
            }
#pragma unroll
            for (int j2 = 0; j2 < 2; ++j2) {
                int br = wc * 32 + j2 * 16 + (lane & 15);
                int gq = kk * 4 + (lane >> 4);
                bfr[j2] = *(const bf16x8*)&Bs[cur][br * 64 + ((gq ^ (br & 7)) * 8)];
            }
#pragma unroll
            for (int i = 0; i < 4; ++i)
#pragma unroll
                for (int j2 = 0; j2 < 2; ++j2)
                    acc[i][j2] = __builtin_amdgcn_mfma_f32_16x16x32_bf16(
                        af[i], bfr[j2], acc[i][j2], 0, 0, 0);
        }
        if (t < 7) writeB(cur ^ 1, bnx, (t + 1) * 64);
        __syncthreads();
        cur ^= 1;
    }
#pragma unroll
    for (int i = 0; i < 4; ++i)
#pragma unroll
        for (int j2 = 0; j2 < 2; ++j2) {
            int row = m0 + wr * 64 + i * 16 + (lane >> 4) * 4;
            int col = n0 + wc * 32 + j2 * 16 + (lane & 15);
#pragma unroll
            for (int q = 0; q < 4; ++q)
                p.Z2bf[(size_t)(row + q) * H2 + col] = f2bf(acc[i][j2][q]);
        }
    const int chunk = mt * 2 + wr;               // 256 chunks
#pragma unroll
    for (int j2 = 0; j2 < 2; ++j2) {
        float s = 0.f, q = 0.f;
#pragma unroll
        for (int i = 0; i < 4; ++i)
#pragma unroll
            for (int qq = 0; qq < 4; ++qq) { float v = acc[i][j2][qq]; s += v; q += v * v; }
        s += __shfl_xor(s, 16); s += __shfl_xor(s, 32);
        q += __shfl_xor(q, 16); q += __shfl_xor(q, 32);
        if (lane < 16) {
            int col = n0 + wc * 32 + j2 * 16 + lane;
            p.psum2[(size_t)chunk * H2 + col] = s;
            p.psq2[(size_t)chunk * H2 + col] = q;
        }
    }
}

// ---------------------------------------------------------------------------
// K5: a2,c2. 32 blocks, 32 lanes/col, tree reduce.
__global__ __launch_bounds__(256) void finstats2_k(Params p) {
    int col = blockIdx.x * 8 + (threadIdx.x >> 5);
    int l32 = threadIdx.x & 31;
    float s = 0.f, q = 0.f;
#pragma unroll
    for (int k = 0; k < 8; ++k) {
        int ch = k * 32 + l32;
        s += p.psum2[(size_t)ch * H2 + col];
        q += p.psq2[(size_t)ch * H2 + col];
    }
#pragma unroll
    for (int m = 1; m <= 16; m <<= 1) {
        s += __shfl_xor(s, m);
        q += __shfl_xor(q, m);
    }
    if (l32 == 0) {
        const float inv = 1.0f / (float)B_ROWS;
        float mean = s * inv;
        float var = q * inv - mean * mean;
        float av = p.g2[col] * rsqrtf(var + EPSV);
        p.a2[col] = av;
        p.c2[col] = p.bt2[col] - mean * av;
    }
}

// ---------------------------------------------------------------------------
// K6: out[b] = partial[b] + sum_c (Z2[b,c]*a2[c] + c2[c]). XCD-chained.
__global__ __launch_bounds__(256) void final_k(Params p) {
    int w = threadIdx.x >> 6, lane = threadIdx.x & 63;
    int j = (int)blockIdx.x;
    int gblk = (j & 7) * 512 + (j >> 3);            // bijective over 4096
    int b = gblk * 4 + w;
    ushort4 z4 = *(const ushort4*)(p.Z2bf + (size_t)b * H2 + lane * 4);
    float4 a = *(const float4*)(p.a2 + lane * 4);
    float4 c = *(const float4*)(p.c2 + lane * 4);
    float v = bf2f(z4.x) * a.x + c.x + bf2f(z4.y) * a.y + c.y
            + bf2f(z4.z) * a.z + c.z + bf2f(z4.w) * a.w + c.w;
#pragma unroll
    for (int m = 1; m < 64; m <<= 1) v += __shfl_xor(v, m);
    if (lane == 0) p.out[b] = p.partial[b] + v;
}

// ---------------------------------------------------------------------------
extern "C" void kernel_launch(void* const* d_in, const int* in_sizes, int n_in,
                              void* d_out, int out_size, void* d_ws, size_t ws_size,
                              hipStream_t stream)
{
    Params p;
    p.Xi   = (const int*)d_in[0];
    p.Xv   = (const float*)d_in[1];
    p.bias = (const float*)d_in[2];
    p.dw1  = (const float*)d_in[3];
    p.db1  = (const float*)d_in[4];
    p.e1   = (const float*)d_in[5];
    p.dw2  = (const float*)d_in[6];
    p.db2  = (const float*)d_in[7];
    p.e2   = (const float*)d_in[8];
    p.W1   = (const float*)d_in[9];
    // d_in[10] = b1: cancels in BN1 -> unused
    p.g1   = (const float*)d_in[11];
    p.bt1  = (const float*)d_in[12];   // col-const shift -> cancels in BN2 -> unused
    p.W2   = (const float*)d_in[13];
    // d_in[14] = b2: cancels in BN2 -> unused
    p.g2   = (const float*)d_in[15];
    p.bt2  = (const float*)d_in[16];

    char* ws = (char*)d_ws;
    size_t off = 0;
    auto alloc = [&](size_t bytes) { char* q = ws + off; off += (bytes + 255) & ~(size_t)255; return q; };
    p.so_bf   = (u16*)alloc((size_t)B_ROWS * D0 * 2);
    p.partial = (float*)alloc((size_t)B_ROWS * 4);
    p.W1T     = (u16*)alloc((size_t)H1 * D0 * 2);
    p.W2T     = (u16*)alloc((size_t)H2 * H1 * 2);
    p.psum1   = (float*)alloc((size_t)256 * H1 * 4);
    p.psq1    = (float*)alloc((size_t)256 * H1 * 4);
    p.psum2   = (float*)alloc((size_t)256 * H2 * 4);
    p.psq2    = (float*)alloc((size_t)256 * H2 * 4);
    p.a1      = (float*)alloc(H1 * 4);
    p.a2      = (float*)alloc(H2 * 4);
    p.c2      = (float*)alloc(H2 * 4);
    p.Z1bf    = (u16*)alloc((size_t)B_ROWS * H1 * 2);
    p.Z2bf    = (u16*)alloc((size_t)B_ROWS * H2 * 2);
    p.out     = (float*)d_out;
    (void)in_sizes; (void)n_in; (void)out_size; (void)ws_size;

    embed_prep_k<<<1024, 256, 0, stream>>>(p);
    gemm1_k    <<<512, 256, 0, stream>>>(p);
    finstats1_k<<<64, 256, 0, stream>>>(p);
    gemm2_k    <<<512, 256, 0, stream>>>(p);
    finstats2_k<<<32, 256, 0, stream>>>(p);
    final_k    <<<B_ROWS / 4, 256, 0, stream>>>(p);
}